// Round 1
// baseline (103.517 us; speedup 1.0000x reference)
//
#include <hip/hip_runtime.h>

#define HW 16384

typedef __attribute__((ext_vector_type(8))) short bf16x8;
typedef __attribute__((ext_vector_type(4))) float f32x4;

// output offsets (floats): cls_score, cls_score_neg, distances, distances_neg, probs_ori
static constexpr size_t OFF0 = 0;
static constexpr size_t OFF1 = 10616832;   // 8*81*16384
static constexpr size_t OFF2 = 21233664;
static constexpr size_t OFF3 = 31850496;
static constexpr size_t OFF4 = 63700992;   // OFF3 + 3*10616832

// ws layout (bytes)
static constexpr size_t WS_R    = 0;        // 81*128 f32   (41472)
static constexpr size_t WS_H1   = 41472;    // 243*128 f32  (124416)
static constexpr size_t WS_H2   = 165888;   // 243*128 f32
static constexpr size_t WS_NEGN = 290304;   // 243*128 f32
static constexpr size_t WS_A    = 414720;   // 21*4*64*16 B (86016) bf16 A-frags

static __device__ __forceinline__ unsigned short f2bf(float f) {
  unsigned int u = __float_as_uint(f);
  u += 0x7fffu + ((u >> 16) & 1u);   // RNE
  return (unsigned short)(u >> 16);
}

// ---------------- prep: reps + first chain stage ----------------
__global__ __launch_bounds__(128) void prep_first(const float* __restrict__ rw,
                                                  const float* __restrict__ rb,
                                                  const float* __restrict__ nw,
                                                  const float* __restrict__ nb,
                                                  float* __restrict__ ws_r,
                                                  float* __restrict__ ws_out) {
  const int b = blockIdx.x;
  const int k = b / 81, o = b % 81;
  const int j = threadIdx.x;
  __shared__ float hrow[128];
  __shared__ float red[2];

  float v = rw[o * 128 + j] + rb[o * 128 + j];
  float sq = v * v;
#pragma unroll
  for (int m = 1; m < 64; m <<= 1) sq += __shfl_xor(sq, m, 64);
  if ((j & 63) == 0) red[j >> 6] = sq;
  __syncthreads();
  float tot = red[0] + red[1];
  float r = v / fmaxf(sqrtf(tot), 1e-12f);
  if (k == 0) ws_r[o * 128 + j] = r;
  hrow[j] = r;
  __syncthreads();

  const float4* Wr = (const float4*)(nw + (((size_t)(k * 3 + 0)) * 128 + j) * 128);
  const float4* H  = (const float4*)hrow;
  float4 a = {0.f, 0.f, 0.f, 0.f};
#pragma unroll
  for (int q = 0; q < 32; ++q) {
    float4 wv = Wr[q]; float4 hv = H[q];
    a.x = fmaf(wv.x, hv.x, a.x); a.y = fmaf(wv.y, hv.y, a.y);
    a.z = fmaf(wv.z, hv.z, a.z); a.w = fmaf(wv.w, hv.w, a.w);
  }
  float acc = (a.x + a.y) + (a.z + a.w);
  acc += nb[(k * 3 + 0) * 128 + j];
  acc = fmaxf(acc, 0.f);                       // relu (l=0 < L-1)
  ws_out[((size_t)(k * 81 + o)) * 128 + j] = acc;
}

// ---------------- prep: generic chain stage ----------------
__global__ __launch_bounds__(128) void prep_stage(const float* __restrict__ in,
                                                  const float* __restrict__ nw,
                                                  const float* __restrict__ nb,
                                                  float* __restrict__ out,
                                                  int l, int do_relu, int do_norm) {
  const int b = blockIdx.x;
  const int k = b / 81, o = b % 81;
  const int j = threadIdx.x;
  __shared__ float hrow[128];
  __shared__ float red[2];

  hrow[j] = in[((size_t)(k * 81 + o)) * 128 + j];
  __syncthreads();

  const float4* Wr = (const float4*)(nw + (((size_t)(k * 3 + l)) * 128 + j) * 128);
  const float4* H  = (const float4*)hrow;
  float4 a = {0.f, 0.f, 0.f, 0.f};
#pragma unroll
  for (int q = 0; q < 32; ++q) {
    float4 wv = Wr[q]; float4 hv = H[q];
    a.x = fmaf(wv.x, hv.x, a.x); a.y = fmaf(wv.y, hv.y, a.y);
    a.z = fmaf(wv.z, hv.z, a.z); a.w = fmaf(wv.w, hv.w, a.w);
  }
  float acc = (a.x + a.y) + (a.z + a.w);
  acc += nb[(k * 3 + l) * 128 + j];
  if (do_relu) acc = fmaxf(acc, 0.f);
  if (do_norm) {
    float sq = acc * acc;
#pragma unroll
    for (int m = 1; m < 64; m <<= 1) sq += __shfl_xor(sq, m, 64);
    if ((j & 63) == 0) red[j >> 6] = sq;
    __syncthreads();
    float tot = red[0] + red[1];
    acc = acc / fmaxf(sqrtf(tot), 1e-12f);
  }
  out[((size_t)(k * 81 + o)) * 128 + j] = acc;
}

// ---------------- prep: pack A-fragments (bf16, MFMA lane order) ----------------
// row = o*4 + s  (s=0: rep, s=1..3: neg k=s-1), rows padded to 336
// frag (mt, ks): lane l holds row mt*16+(l&15), k = ks*32+(l>>4)*8 .. +7
__global__ __launch_bounds__(64) void prep_pack(const float* __restrict__ ws_r,
                                                const float* __restrict__ ws_negn,
                                                bf16x8* __restrict__ wsA) {
  const int mt = blockIdx.x >> 2, ks = blockIdx.x & 3;
  const int l = threadIdx.x;
  const int row = mt * 16 + (l & 15);
  const int o = row >> 2, s = row & 3;
  const int k0 = ks * 32 + (l >> 4) * 8;
  bf16x8 r = {0, 0, 0, 0, 0, 0, 0, 0};
  if (o < 81) {
    const float* src = (s == 0) ? (ws_r + (size_t)o * 128)
                                : (ws_negn + ((size_t)((s - 1) * 81 + o)) * 128);
#pragma unroll
    for (int jj = 0; jj < 8; ++jj) r[jj] = (short)f2bf(src[k0 + jj]);
  }
  wsA[(mt * 4 + ks) * 64 + l] = r;
}

// ---------------- main fused kernel ----------------
__global__ __launch_bounds__(256) void main_kernel(const float* __restrict__ x,
                                                   const bf16x8* __restrict__ wsA,
                                                   float* __restrict__ out) {
  __shared__ __align__(16) char eLds[32768];   // 128 px * 128 ch bf16, XOR-swizzled
  __shared__ float ss[8][128];
  __shared__ float invn[128];

  const int b = blockIdx.x;
  const int n = b >> 7;
  const int p0 = (b & 127) << 7;
  const int t = threadIdx.x;
  const float* xb = x + ((size_t)n * 128) * HW + p0;

  // ---- build E tile (raw x as bf16; norm folded into epilogue) ----
  {
    const int pq = (t & 31) * 4;   // pixel quad
    const int cg = t >> 5;         // channel group 0..7
    float a0 = 0.f, a1 = 0.f, a2 = 0.f, a3 = 0.f;
#pragma unroll
    for (int i = 0; i < 16; ++i) {
      const int c = i * 8 + cg;
      float4 v = *(const float4*)(xb + (size_t)c * HW + pq);
      a0 = fmaf(v.x, v.x, a0); a1 = fmaf(v.y, v.y, a1);
      a2 = fmaf(v.z, v.z, a2); a3 = fmaf(v.w, v.w, a3);
      const int c2 = c * 2;
      *(unsigned short*)(eLds + (((pq + 0) * 256 + c2) ^ (((pq + 0) & 7) << 4))) = f2bf(v.x);
      *(unsigned short*)(eLds + (((pq + 1) * 256 + c2) ^ (((pq + 1) & 7) << 4))) = f2bf(v.y);
      *(unsigned short*)(eLds + (((pq + 2) * 256 + c2) ^ (((pq + 2) & 7) << 4))) = f2bf(v.z);
      *(unsigned short*)(eLds + (((pq + 3) * 256 + c2) ^ (((pq + 3) & 7) << 4))) = f2bf(v.w);
    }
    float4 st = {a0, a1, a2, a3};
    *(float4*)&ss[cg][pq] = st;
  }
  __syncthreads();
  if (t < 128) {
    float s = 0.f;
#pragma unroll
    for (int g = 0; g < 8; ++g) s += ss[g][t];
    invn[t] = 1.f / fmaxf(sqrtf(s), 1e-12f);
  }
  __syncthreads();

  const int lane = t & 63;
  const int wv = t >> 6;        // wave 0..3, owns pixels [wv*32, wv*32+32)
  const int og = lane >> 4;     // o within 4-group of the m-tile

  // ---- B-fragments (kept in registers, reused across all 21 m-tiles) ----
  bf16x8 bfrag[2][4];
  float ivp[2];
#pragma unroll
  for (int u = 0; u < 2; ++u) {
    const int p = (wv * 2 + u) * 16 + (lane & 15);
#pragma unroll
    for (int ks = 0; ks < 4; ++ks) {
      const int addr = (p * 256 + ks * 64 + (lane >> 4) * 16) ^ ((p & 7) << 4);
      bfrag[u][ks] = *(const bf16x8*)(eLds + addr);
    }
    ivp[u] = invn[p];
  }

  float probs_arr[42];

#pragma unroll
  for (int mt = 0; mt < 21; ++mt) {
    bf16x8 afr[4];
#pragma unroll
    for (int ks = 0; ks < 4; ++ks) afr[ks] = wsA[(mt * 4 + ks) * 64 + lane];
    f32x4 c0 = {0.f, 0.f, 0.f, 0.f}, c1 = {0.f, 0.f, 0.f, 0.f};
#pragma unroll
    for (int ks = 0; ks < 4; ++ks) {
      c0 = __builtin_amdgcn_mfma_f32_16x16x32_bf16(afr[ks], bfrag[0][ks], c0, 0, 0, 0);
      c1 = __builtin_amdgcn_mfma_f32_16x16x32_bf16(afr[ks], bfrag[1][ks], c1, 0, 0, 0);
    }
    const int o = mt * 4 + og;
    const bool valid = (o < 81);
#pragma unroll
    for (int u = 0; u < 2; ++u) {
      const f32x4 c = u ? c1 : c0;
      const float iv = ivp[u];
      float q0 = fmaxf(2.f - 2.f * (c[0] * iv), 0.f);
      float d0 = sqrtf(q0);
      float d1 = sqrtf(fmaxf(2.f - 2.f * (c[1] * iv), 0.f));
      float d2 = sqrtf(fmaxf(2.f - 2.f * (c[2] * iv), 0.f));
      float d3 = sqrtf(fmaxf(2.f - 2.f * (c[3] * iv), 0.f));
      float dmin = fminf(d1, fminf(d2, d3));
      float pneg = __expf(-2.f * dmin * dmin);     // max_k exp(-2 d_k^2)
      float pori = __expf(-2.f * q0);
      float tt = d0 + 0.3f * fmaxf(2.f - dmin, 0.f);
      float pr = __expf(-2.f * tt * tt);
      probs_arr[mt * 2 + u] = valid ? pr : 0.f;
      if (valid) {
        const int pimg = p0 + (wv * 2 + u) * 16 + (lane & 15);
        const size_t base = ((size_t)(n * 81 + o)) * HW + pimg;
        out[OFF2 + base] = d0;
        out[OFF4 + base] = pori;
        out[OFF1 + base] = pneg;
        const size_t b3 = ((size_t)((n * 81 + o) * 3)) * HW + pimg;
        out[OFF3 + b3] = d1;
        out[OFF3 + b3 + HW] = d2;
        out[OFF3 + b3 + 2 * HW] = d3;
      }
    }
  }

  // ---- cls_score: normalize probs over o per pixel ----
#pragma unroll
  for (int u = 0; u < 2; ++u) {
    float s = 0.f;
#pragma unroll
    for (int mt = 0; mt < 21; ++mt) s += probs_arr[mt * 2 + u];
    s += __shfl_xor(s, 16, 64);
    s += __shfl_xor(s, 32, 64);
    const float is = 1.f / s;
    const int pimg = p0 + (wv * 2 + u) * 16 + (lane & 15);
#pragma unroll
    for (int mt = 0; mt < 21; ++mt) {
      const int o = mt * 4 + og;
      if (o < 81) {
        const size_t base = ((size_t)(n * 81 + o)) * HW + pimg;
        out[OFF0 + base] = probs_arr[mt * 2 + u] * is;
      }
    }
  }
}

extern "C" void kernel_launch(void* const* d_in, const int* in_sizes, int n_in,
                              void* d_out, int out_size, void* d_ws, size_t ws_size,
                              hipStream_t stream) {
  const float* x  = (const float*)d_in[0];
  const float* rw = (const float*)d_in[1];
  const float* rb = (const float*)d_in[2];
  const float* nw = (const float*)d_in[3];
  const float* nb = (const float*)d_in[4];
  float* out = (float*)d_out;
  char* ws = (char*)d_ws;
  float* ws_r    = (float*)(ws + WS_R);
  float* ws_h1   = (float*)(ws + WS_H1);
  float* ws_h2   = (float*)(ws + WS_H2);
  float* ws_negn = (float*)(ws + WS_NEGN);
  bf16x8* wsA    = (bf16x8*)(ws + WS_A);

  hipLaunchKernelGGL(prep_first, dim3(243), dim3(128), 0, stream, rw, rb, nw, nb, ws_r, ws_h1);
  hipLaunchKernelGGL(prep_stage, dim3(243), dim3(128), 0, stream, ws_h1, nw, nb, ws_h2, 1, 1, 0);
  hipLaunchKernelGGL(prep_stage, dim3(243), dim3(128), 0, stream, ws_h2, nw, nb, ws_negn, 2, 0, 1);
  hipLaunchKernelGGL(prep_pack, dim3(84), dim3(64), 0, stream, ws_r, ws_negn, wsA);
  hipLaunchKernelGGL(main_kernel, dim3(1024), dim3(256), 0, stream, x, wsA, out);
}

// Round 2
// 97.927 us; speedup vs baseline: 1.0571x; 1.0571x over previous
//
#include <hip/hip_runtime.h>

#define HW 16384

typedef __attribute__((ext_vector_type(8))) short bf16x8;
typedef __attribute__((ext_vector_type(4))) float f32x4;

// output offsets (floats): cls_score, cls_score_neg, distances, distances_neg, probs_ori
static constexpr size_t OFF0 = 0;
static constexpr size_t OFF1 = 10616832;   // 8*81*16384
static constexpr size_t OFF2 = 21233664;
static constexpr size_t OFF3 = 31850496;
static constexpr size_t OFF4 = 63700992;   // OFF3 + 3*10616832

static __device__ __forceinline__ unsigned short f2bf(float f) {
  unsigned int u = __float_as_uint(f);
  u += 0x7fffu + ((u >> 16) & 1u);   // RNE
  return (unsigned short)(u >> 16);
}

// write one (row R, channel j) bf16 value into the MFMA A-frag layout
// frag (mt,ks): lane l holds row mt*16+(l&15), k = ks*32+(l>>4)*8 .. +7
static __device__ __forceinline__ void frag_write(unsigned short* wsA, int R, int j,
                                                  unsigned short v) {
  const int mt = R >> 4;
  const int ks = j >> 5;
  const int hi = (j >> 3) & 3;
  const int jj = j & 7;
  const int lane = hi * 16 + (R & 15);
  wsA[((size_t)((mt * 4 + ks) * 64 + lane)) * 8 + jj] = v;
}

// ---------------- fused prep: reps + full 3-stage chain + norm + frag pack ----------------
// one block per (k,o); rows R = o*4 + s (s=0: rep, s=1..3: neg k=s-1)
__global__ __launch_bounds__(128) void prep_all(const float* __restrict__ rw,
                                                const float* __restrict__ rb,
                                                const float* __restrict__ nw,
                                                const float* __restrict__ nb,
                                                unsigned short* __restrict__ wsA) {
  const int b = blockIdx.x;
  const int k = b / 81, o = b % 81;
  const int j = threadIdx.x;
  __shared__ __align__(16) float hrow[128];
  __shared__ float red[2];

  // r = normalize(rw + rb)
  float v = rw[o * 128 + j] + rb[o * 128 + j];
  float sq = v * v;
#pragma unroll
  for (int m = 1; m < 64; m <<= 1) sq += __shfl_xor(sq, m, 64);
  if ((j & 63) == 0) red[j >> 6] = sq;
  __syncthreads();
  const float r = v / fmaxf(sqrtf(red[0] + red[1]), 1e-12f);
  __syncthreads();                  // red consumed by all before reuse
  hrow[j] = r;
  __syncthreads();

  float acc = 0.f;
#pragma unroll
  for (int l = 0; l < 3; ++l) {
    const float4* Wr = (const float4*)(nw + (((size_t)(k * 3 + l)) * 128 + j) * 128);
    const float4* H  = (const float4*)hrow;
    float4 a = {0.f, 0.f, 0.f, 0.f};
#pragma unroll
    for (int q = 0; q < 32; ++q) {
      float4 wv = Wr[q]; float4 hv = H[q];
      a.x = fmaf(wv.x, hv.x, a.x); a.y = fmaf(wv.y, hv.y, a.y);
      a.z = fmaf(wv.z, hv.z, a.z); a.w = fmaf(wv.w, hv.w, a.w);
    }
    acc = (a.x + a.y) + (a.z + a.w) + nb[(k * 3 + l) * 128 + j];
    if (l < 2) acc = fmaxf(acc, 0.f);
    __syncthreads();
    if (l < 2) hrow[j] = acc;
    __syncthreads();
  }

  // normalize final chain output
  float sq2 = acc * acc;
#pragma unroll
  for (int m = 1; m < 64; m <<= 1) sq2 += __shfl_xor(sq2, m, 64);
  if ((j & 63) == 0) red[j >> 6] = sq2;
  __syncthreads();
  const float accn = acc / fmaxf(sqrtf(red[0] + red[1]), 1e-12f);

  frag_write(wsA, o * 4 + k + 1, j, f2bf(accn));
  if (k == 0) frag_write(wsA, o * 4, j, f2bf(r));
  if (b == 0) {            // zero the pad rows 324..335 (o = 81..83)
#pragma unroll
    for (int R = 324; R < 336; ++R) frag_write(wsA, R, j, (unsigned short)0);
  }
}

// ---------------- main fused kernel ----------------
__global__ __launch_bounds__(256) void main_kernel(const float* __restrict__ x,
                                                   const bf16x8* __restrict__ wsA,
                                                   float* __restrict__ out) {
  __shared__ __align__(16) char eLds[32768];   // 128 px * 128 ch bf16, XOR-swizzled
  __shared__ float ss[8][128];
  __shared__ float invn[128];

  const int b = blockIdx.x;
  const int n = b >> 7;
  const int p0 = (b & 127) << 7;
  const int t = threadIdx.x;
  const float* xb = x + ((size_t)n * 128) * HW + p0;

  // ---- build E tile: pack 4 channels/px -> ds_write_b64, swizzle on (px>>2)&7 ----
  {
    const int pq = (t & 31) * 4;     // pixel quad base; px>>2 == t&31 for all 4 px
    const int cg = t >> 5;           // channel group 0..7 (4 channels each per i)
    const int swz = (t & 7) << 4;    // ((px>>2)&7)<<4
    float a0 = 0.f, a1 = 0.f, a2 = 0.f, a3 = 0.f;
#pragma unroll
    for (int i = 0; i < 4; ++i) {
      const int c0 = i * 32 + cg * 4;
      float4 v0 = *(const float4*)(xb + (size_t)(c0 + 0) * HW + pq);
      float4 v1 = *(const float4*)(xb + (size_t)(c0 + 1) * HW + pq);
      float4 v2 = *(const float4*)(xb + (size_t)(c0 + 2) * HW + pq);
      float4 v3 = *(const float4*)(xb + (size_t)(c0 + 3) * HW + pq);
      a0 = fmaf(v0.x, v0.x, fmaf(v1.x, v1.x, fmaf(v2.x, v2.x, fmaf(v3.x, v3.x, a0))));
      a1 = fmaf(v0.y, v0.y, fmaf(v1.y, v1.y, fmaf(v2.y, v2.y, fmaf(v3.y, v3.y, a1))));
      a2 = fmaf(v0.z, v0.z, fmaf(v1.z, v1.z, fmaf(v2.z, v2.z, fmaf(v3.z, v3.z, a2))));
      a3 = fmaf(v0.w, v0.w, fmaf(v1.w, v1.w, fmaf(v2.w, v2.w, fmaf(v3.w, v3.w, a3))));
      uint2 w;
      w.x = (unsigned)f2bf(v0.x) | ((unsigned)f2bf(v1.x) << 16);
      w.y = (unsigned)f2bf(v2.x) | ((unsigned)f2bf(v3.x) << 16);
      *(uint2*)(eLds + (((pq + 0) * 256 + c0 * 2) ^ swz)) = w;
      w.x = (unsigned)f2bf(v0.y) | ((unsigned)f2bf(v1.y) << 16);
      w.y = (unsigned)f2bf(v2.y) | ((unsigned)f2bf(v3.y) << 16);
      *(uint2*)(eLds + (((pq + 1) * 256 + c0 * 2) ^ swz)) = w;
      w.x = (unsigned)f2bf(v0.z) | ((unsigned)f2bf(v1.z) << 16);
      w.y = (unsigned)f2bf(v2.z) | ((unsigned)f2bf(v3.z) << 16);
      *(uint2*)(eLds + (((pq + 2) * 256 + c0 * 2) ^ swz)) = w;
      w.x = (unsigned)f2bf(v0.w) | ((unsigned)f2bf(v1.w) << 16);
      w.y = (unsigned)f2bf(v2.w) | ((unsigned)f2bf(v3.w) << 16);
      *(uint2*)(eLds + (((pq + 3) * 256 + c0 * 2) ^ swz)) = w;
    }
    float4 st = {a0, a1, a2, a3};
    *(float4*)&ss[cg][pq] = st;
  }
  __syncthreads();
  if (t < 128) {
    float s = 0.f;
#pragma unroll
    for (int g = 0; g < 8; ++g) s += ss[g][t];
    invn[t] = 1.f / fmaxf(sqrtf(s), 1e-12f);
  }
  __syncthreads();

  const int lane = t & 63;
  const int wv = t >> 6;        // wave 0..3, owns pixels [wv*32, wv*32+32)
  const int og = lane >> 4;     // o within 4-group of the m-tile

  // ---- B-fragments (registers, reused across all 21 m-tiles) ----
  bf16x8 bfrag[2][4];
  float ivp[2];
#pragma unroll
  for (int u = 0; u < 2; ++u) {
    const int p = (wv * 2 + u) * 16 + (lane & 15);
    const int swzr = ((p >> 2) & 7) << 4;
#pragma unroll
    for (int ks = 0; ks < 4; ++ks) {
      const int addr = (p * 256 + ks * 64 + (lane >> 4) * 16) ^ swzr;
      bfrag[u][ks] = *(const bf16x8*)(eLds + addr);
    }
    ivp[u] = invn[p];
  }

  float probs_arr[42];

#pragma unroll
  for (int mt = 0; mt < 21; ++mt) {
    bf16x8 afr[4];
#pragma unroll
    for (int ks = 0; ks < 4; ++ks) afr[ks] = wsA[(mt * 4 + ks) * 64 + lane];
    f32x4 c0 = {0.f, 0.f, 0.f, 0.f}, c1 = {0.f, 0.f, 0.f, 0.f};
#pragma unroll
    for (int ks = 0; ks < 4; ++ks) {
      c0 = __builtin_amdgcn_mfma_f32_16x16x32_bf16(afr[ks], bfrag[0][ks], c0, 0, 0, 0);
      c1 = __builtin_amdgcn_mfma_f32_16x16x32_bf16(afr[ks], bfrag[1][ks], c1, 0, 0, 0);
    }
    const int o = mt * 4 + og;
    const bool valid = (o < 81);
#pragma unroll
    for (int u = 0; u < 2; ++u) {
      const f32x4 c = u ? c1 : c0;
      const float iv = ivp[u];
      float q0 = fmaxf(2.f - 2.f * (c[0] * iv), 0.f);
      float d0 = sqrtf(q0);
      float d1 = sqrtf(fmaxf(2.f - 2.f * (c[1] * iv), 0.f));
      float d2 = sqrtf(fmaxf(2.f - 2.f * (c[2] * iv), 0.f));
      float d3 = sqrtf(fmaxf(2.f - 2.f * (c[3] * iv), 0.f));
      float dmin = fminf(d1, fminf(d2, d3));
      float pneg = __expf(-2.f * dmin * dmin);     // max_k exp(-2 d_k^2)
      float pori = __expf(-2.f * q0);
      float tt = d0 + 0.3f * fmaxf(2.f - dmin, 0.f);
      float pr = __expf(-2.f * tt * tt);
      probs_arr[mt * 2 + u] = valid ? pr : 0.f;
      if (valid) {
        const int pimg = p0 + (wv * 2 + u) * 16 + (lane & 15);
        const size_t base = ((size_t)(n * 81 + o)) * HW + pimg;
        out[OFF2 + base] = d0;
        out[OFF4 + base] = pori;
        out[OFF1 + base] = pneg;
        const size_t b3 = ((size_t)((n * 81 + o) * 3)) * HW + pimg;
        out[OFF3 + b3] = d1;
        out[OFF3 + b3 + HW] = d2;
        out[OFF3 + b3 + 2 * HW] = d3;
      }
    }
  }

  // ---- cls_score: normalize probs over o per pixel ----
#pragma unroll
  for (int u = 0; u < 2; ++u) {
    float s = 0.f;
#pragma unroll
    for (int mt = 0; mt < 21; ++mt) s += probs_arr[mt * 2 + u];
    s += __shfl_xor(s, 16, 64);
    s += __shfl_xor(s, 32, 64);
    const float is = 1.f / s;
    const int pimg = p0 + (wv * 2 + u) * 16 + (lane & 15);
#pragma unroll
    for (int mt = 0; mt < 21; ++mt) {
      const int o = mt * 4 + og;
      if (o < 81) {
        const size_t base = ((size_t)(n * 81 + o)) * HW + pimg;
        out[OFF0 + base] = probs_arr[mt * 2 + u] * is;
      }
    }
  }
}

extern "C" void kernel_launch(void* const* d_in, const int* in_sizes, int n_in,
                              void* d_out, int out_size, void* d_ws, size_t ws_size,
                              hipStream_t stream) {
  const float* x  = (const float*)d_in[0];
  const float* rw = (const float*)d_in[1];
  const float* rb = (const float*)d_in[2];
  const float* nw = (const float*)d_in[3];
  const float* nb = (const float*)d_in[4];
  float* out = (float*)d_out;
  unsigned short* wsA_us = (unsigned short*)d_ws;
  const bf16x8* wsA = (const bf16x8*)d_ws;

  hipLaunchKernelGGL(prep_all, dim3(243), dim3(128), 0, stream, rw, rb, nw, nb, wsA_us);
  hipLaunchKernelGGL(main_kernel, dim3(1024), dim3(256), 0, stream, x, wsA, out);
}